// Round 1
// baseline (130.452 us; speedup 1.0000x reference)
//
#include <hip/hip_runtime.h>
#include <hip/hip_bf16.h>
#include <math.h>

// Problem constants (from reference)
#define N_  64
#define TC_ 256
#define K_  32
#define TK_ 64
#define D_  256
#define TF_ (TK_ + TC_)   // 320 tokens in full_enc

// ---------------------------------------------------------------------------
// k0: zero the workspace accumulators (ws is poisoned 0xAA before every call)
// ---------------------------------------------------------------------------
__global__ void k0_zero(float* __restrict__ ctx_sum, int* __restrict__ ctx_len) {
    int idx = blockIdx.x * 256 + threadIdx.x;
    if (idx < N_ * D_) ctx_sum[idx] = 0.f;
    if (idx < N_)      ctx_len[idx] = 0;
}

// ---------------------------------------------------------------------------
// k1: context gather. Writes ctx part of full_enc/full_mask, accumulates
//     raw ctx sum (pre-normalization) and ctx length.
// grid = N*8 blocks (32 tokens per block), 256 threads (one per dim d)
// ---------------------------------------------------------------------------
__global__ __launch_bounds__(256) void k1_ctx(
        const int* __restrict__ src, const float* __restrict__ embed,
        float* __restrict__ out_enc, float* __restrict__ out_mask,
        float* __restrict__ ctx_sum, int* __restrict__ ctx_len) {
    const int n = blockIdx.x >> 3;
    const int c = blockIdx.x & 7;          // token chunk: 32 tokens
    const int d = threadIdx.x;

    __shared__ int toks[32];
    if (d < 32) toks[d] = src[n * TC_ + c * 32 + d];
    __syncthreads();

    float acc = 0.f;
    #pragma unroll 4
    for (int tt = 0; tt < 32; ++tt) {
        const int tok = toks[tt];
        float v = 0.f;
        if (tok != 0) v = embed[(size_t)tok * D_ + d];
        out_enc[((size_t)n * TF_ + TK_ + c * 32 + tt) * D_ + d] = v;
        acc += v;
    }
    atomicAdd(&ctx_sum[n * D_ + d], acc);

    if (d < 32) {
        const int m = (toks[d] != 0);
        out_mask[n * TF_ + TK_ + c * 32 + d] = m ? 1.f : 0.f;
        if (m) atomicAdd(&ctx_len[n], 1);   // compiler coalesces per-wave
    }
}

// ---------------------------------------------------------------------------
// k2: knowledge pooling + attention score. One block per (n,k).
//     Pools 64 embedding rows in registers (one dim per thread), dots with
//     the raw ctx sum, applies both sqrt(D*len) normalizations.
// grid = N*K = 2048 blocks, 256 threads
// ---------------------------------------------------------------------------
__global__ __launch_bounds__(256) void k2_know(
        const int* __restrict__ know, const int* __restrict__ ckm,
        const float* __restrict__ embed,
        const float* __restrict__ ctx_sum, const int* __restrict__ ctx_len,
        float* __restrict__ out_attn, float* __restrict__ ws_score) {
    const int n = blockIdx.x >> 5;
    const int k = blockIdx.x & (K_ - 1);
    const int d = threadIdx.x;

    __shared__ int   toks[TK_];
    __shared__ float red[4];

    const int ck = ckm[n * K_ + k];
    if (d < TK_) toks[d] = know[((size_t)n * K_ + k) * TK_ + d];
    __syncthreads();

    float acc = 0.f;
    if (ck) {
        #pragma unroll 8
        for (int t = 0; t < TK_; ++t) {
            const int tok = toks[t];
            if (tok != 0) acc += embed[(size_t)tok * D_ + d];
        }
    }

    // know_len via ballot on the first wave (threads 0..63)
    int lk = 0;
    if (d < 64) {
        unsigned long long ball = __ballot(ck && (toks[d] != 0));
        lk = __popcll(ball);               // meaningful on lane 0 (uniform anyway)
    }

    // dot(know_sum, ctx_sum) block reduction
    float p = acc * ctx_sum[n * D_ + d];
    #pragma unroll
    for (int o = 32; o > 0; o >>= 1) p += __shfl_down(p, o, 64);
    if ((d & 63) == 0) red[d >> 6] = p;
    __syncthreads();

    if (d == 0) {
        const float dot = red[0] + red[1] + red[2] + red[3];
        int lc = ctx_len[n]; if (lc < 1) lc = 1;
        if (lk < 1) lk = 1;
        const float score =
            dot / (sqrtf((float)D_ * (float)lc) * sqrtf((float)D_ * (float)lk));
        out_attn[n * K_ + k] = ck ? score : 0.f;
        ws_score[n * K_ + k] = ck ? score : -INFINITY;
    }
}

// ---------------------------------------------------------------------------
// k3: select best knowledge span (argmax, first-max tie-break, matching
//     jnp.argmax) or cs_ids if use_cs_ids; gather its rows into slots [0,64).
// grid = N*4 blocks (16 tokens per block), 256 threads
// ---------------------------------------------------------------------------
__global__ __launch_bounds__(256) void k3_sel(
        const int* __restrict__ know, const int* __restrict__ ckm,
        const int* __restrict__ cs_ids, const int* __restrict__ use_flag,
        const float* __restrict__ embed, const float* __restrict__ ws_score,
        float* __restrict__ out_enc, float* __restrict__ out_mask) {
    const int n = blockIdx.x >> 2;
    const int c = blockIdx.x & 3;          // token chunk: 16 tokens
    const int d = threadIdx.x;

    // uniform redundant argmax (32 cached reads; no divergence)
    int cs = 0;
    if (use_flag[0]) {
        cs = cs_ids[n];
    } else {
        float best = -INFINITY;
        #pragma unroll
        for (int j = 0; j < K_; ++j) {
            const float s = ws_score[n * K_ + j];
            if (s > best) { best = s; cs = j; }
        }
    }
    const int ck = ckm[n * K_ + cs];

    __shared__ int toks[16];
    if (d < 16) toks[d] = know[((size_t)n * K_ + cs) * TK_ + c * 16 + d];
    __syncthreads();

    #pragma unroll
    for (int tt = 0; tt < 16; ++tt) {
        const int tok = toks[tt];
        const int m = ck && (tok != 0);
        float v = 0.f;
        if (m) v = embed[(size_t)tok * D_ + d];
        out_enc[((size_t)n * TF_ + c * 16 + tt) * D_ + d] = v;
    }
    if (d < 16) {
        const int m = ck && (toks[d] != 0);
        out_mask[n * TF_ + c * 16 + d] = m ? 1.f : 0.f;
    }
}

// ---------------------------------------------------------------------------
extern "C" void kernel_launch(void* const* d_in, const int* in_sizes, int n_in,
                              void* d_out, int out_size, void* d_ws, size_t ws_size,
                              hipStream_t stream) {
    const int*   src      = (const int*)d_in[0];   // [N,TC]
    const int*   know     = (const int*)d_in[1];   // [N,K,TK]
    const int*   ckm      = (const int*)d_in[2];   // [N,K] (bool -> int32 assumed)
    const int*   cs_ids   = (const int*)d_in[3];   // [N]
    const int*   use_flag = (const int*)d_in[4];   // scalar
    const float* embed    = (const float*)d_in[5]; // [V,D]

    float* out      = (float*)d_out;
    float* out_enc  = out;                                   // [N,TF,D]
    float* out_mask = out + (size_t)N_ * TF_ * D_;           // [N,TF]
    float* out_attn = out_mask + (size_t)N_ * TF_;           // [N,K]

    float* ctx_sum  = (float*)d_ws;                          // [N,D]
    int*   ctx_len  = (int*)(ctx_sum + N_ * D_);             // [N]
    float* ws_score = (float*)(ctx_len + N_);                // [N,K]

    hipLaunchKernelGGL(k0_zero, dim3((N_ * D_ + 255) / 256), dim3(256), 0, stream,
                       ctx_sum, ctx_len);
    hipLaunchKernelGGL(k1_ctx, dim3(N_ * 8), dim3(256), 0, stream,
                       src, embed, out_enc, out_mask, ctx_sum, ctx_len);
    hipLaunchKernelGGL(k2_know, dim3(N_ * K_), dim3(256), 0, stream,
                       know, ckm, embed, ctx_sum, ctx_len, out_attn, ws_score);
    hipLaunchKernelGGL(k3_sel, dim3(N_ * 4), dim3(256), 0, stream,
                       know, ckm, cs_ids, use_flag, embed, ws_score,
                       out_enc, out_mask);
}

// Round 7
// 110.295 us; speedup vs baseline: 1.1828x; 1.1828x over previous
//
#include <hip/hip_runtime.h>
#include <math.h>

// Problem constants (from reference)
#define N_  64
#define TC_ 256
#define K_  32
#define TK_ 64
#define D_  256
#define D4_ (D_ / 4)      // 64 float4 per embedding row
#define TF_ (TK_ + TC_)   // 320 tokens in full_enc

// ---------------------------------------------------------------------------
// kA: context gather (float4). Writes ctx part of full_enc/full_mask and
//     per-chunk partial sums/lengths to ws (all slots written -> no zeroing,
//     no atomics).
// grid = N*8 (32 tokens per block), block = 256 (4 waves x 64 lanes)
// One wave moves one embedding row per iteration (64 lanes x 16B = 1KB).
// ---------------------------------------------------------------------------
__global__ __launch_bounds__(256) void kA_ctx(
        const int* __restrict__ src, const float4* __restrict__ embed4,
        float4* __restrict__ out_enc4, float* __restrict__ out_mask,
        float4* __restrict__ ws_part4, int* __restrict__ ws_clen) {
    const int n = blockIdx.x >> 3;
    const int c = blockIdx.x & 7;
    const int tid = threadIdx.x;
    const int w = tid >> 6, l = tid & 63;

    __shared__ int toks[32];
    __shared__ float4 part[4][64];

    if (tid < 32) {
        const int tok = src[n * TC_ + c * 32 + tid];
        toks[tid] = tok;
        out_mask[n * TF_ + TK_ + c * 32 + tid] = tok ? 1.f : 0.f;
    }
    __syncthreads();

    float4 acc = {0.f, 0.f, 0.f, 0.f};
    #pragma unroll
    for (int i = 0; i < 8; ++i) {
        const int t = w * 8 + i;                 // wave w owns tokens [8w, 8w+8)
        const int tok = toks[t];                 // wave-uniform -> scalar branch
        float4 v = {0.f, 0.f, 0.f, 0.f};
        if (tok) v = embed4[(size_t)tok * D4_ + l];
        out_enc4[((size_t)n * TF_ + TK_ + c * 32 + t) * D4_ + l] = v;
        acc.x += v.x; acc.y += v.y; acc.z += v.z; acc.w += v.w;
    }
    part[w][l] = acc;
    __syncthreads();

    if (w == 0) {
        float4 a = part[0][l], b = part[1][l], p2 = part[2][l], p3 = part[3][l];
        a.x += b.x + p2.x + p3.x;
        a.y += b.y + p2.y + p3.y;
        a.z += b.z + p2.z + p3.z;
        a.w += b.w + p2.w + p3.w;
        ws_part4[(size_t)(n * 8 + c) * D4_ + l] = a;
        const unsigned long long ball = __ballot(l < 32 && toks[l] != 0);
        if (l == 0) ws_clen[n * 8 + c] = __popcll(ball);
    }
}

// ---------------------------------------------------------------------------
// kB: knowledge pooling + attention score (float4). One block per (n,k):
//     4 waves x 16 token-rows each, per-lane float4 accumulator, dot with
//     the (chunk-summed) ctx vector, shuffle+LDS reduction.
// grid = N*K = 2048, block = 256
// ---------------------------------------------------------------------------
__global__ __launch_bounds__(256) void kB_know(
        const int* __restrict__ know, const int* __restrict__ ckm,
        const float4* __restrict__ embed4,
        const float4* __restrict__ ws_part4, const int* __restrict__ ws_clen,
        float* __restrict__ out_attn, float* __restrict__ ws_score) {
    const int n = blockIdx.x >> 5;
    const int k = blockIdx.x & (K_ - 1);
    const int tid = threadIdx.x;
    const int w = tid >> 6, l = tid & 63;

    __shared__ int toks[TK_];
    __shared__ float redp[4];
    __shared__ int lk_sh;

    if (tid < TK_) toks[tid] = know[((size_t)n * K_ + k) * TK_ + tid];
    __syncthreads();

    const int ck = ckm[n * K_ + k];

    // reconstruct ctx raw sum at this lane's 4 dims (8 chunk partials)
    float4 ctx = {0.f, 0.f, 0.f, 0.f};
    #pragma unroll
    for (int c = 0; c < 8; ++c) {
        const float4 v = ws_part4[(size_t)(n * 8 + c) * D4_ + l];
        ctx.x += v.x; ctx.y += v.y; ctx.z += v.z; ctx.w += v.w;
    }

    // pool 16 token-rows per wave
    float4 acc = {0.f, 0.f, 0.f, 0.f};
    if (ck) {
        #pragma unroll
        for (int i = 0; i < 16; ++i) {
            const int tok = toks[w * 16 + i];    // wave-uniform branch
            if (tok) {
                const float4 v = embed4[(size_t)tok * D4_ + l];
                acc.x += v.x; acc.y += v.y; acc.z += v.z; acc.w += v.w;
            }
        }
    }

    // dot(know_sum, ctx_sum): per-lane partial, wave shuffle, LDS combine
    float p = acc.x * ctx.x + acc.y * ctx.y + acc.z * ctx.z + acc.w * ctx.w;
    #pragma unroll
    for (int o = 32; o > 0; o >>= 1) p += __shfl_down(p, o, 64);
    if (l == 0) redp[w] = p;
    if (w == 0) {
        const unsigned long long ball = __ballot(toks[l] != 0);
        if (l == 0) lk_sh = __popcll(ball);
    }
    __syncthreads();

    if (tid == 0) {
        const float dot = redp[0] + redp[1] + redp[2] + redp[3];
        int lc = 0;
        #pragma unroll
        for (int c = 0; c < 8; ++c) lc += ws_clen[n * 8 + c];
        if (lc < 1) lc = 1;
        int lk = ck ? lk_sh : 0;                 // know_mask includes ck
        if (lk < 1) lk = 1;
        const float score =
            dot / (sqrtf((float)(D_ * lc)) * sqrtf((float)(D_ * lk)));
        out_attn[n * K_ + k] = ck ? score : 0.f;
        ws_score[n * K_ + k] = ck ? score : -INFINITY;
    }
}

// ---------------------------------------------------------------------------
// kC: argmax-select (first-max tie-break, matching jnp.argmax) or cs_ids;
//     gather the selected span into token slots [0, TK). float4.
// grid = N*4 (16 tokens per block), block = 256
// ---------------------------------------------------------------------------
__global__ __launch_bounds__(256) void kC_sel(
        const int* __restrict__ know, const int* __restrict__ ckm,
        const int* __restrict__ cs_ids, const int* __restrict__ use_flag,
        const float4* __restrict__ embed4, const float* __restrict__ ws_score,
        float4* __restrict__ out_enc4, float* __restrict__ out_mask) {
    const int n = blockIdx.x >> 2;
    const int c = blockIdx.x & 3;
    const int tid = threadIdx.x;
    const int w = tid >> 6, l = tid & 63;

    // uniform redundant argmax (cached loads, no divergence)
    int cs = 0;
    if (use_flag[0]) {
        cs = cs_ids[n];
    } else {
        float best = -INFINITY;
        #pragma unroll
        for (int j = 0; j < K_; ++j) {
            const float s = ws_score[n * K_ + j];
            if (s > best) { best = s; cs = j; }
        }
    }
    const int ck = ckm[n * K_ + cs];

    __shared__ int toks[16];
    if (tid < 16) {
        const int tok = know[((size_t)n * K_ + cs) * TK_ + c * 16 + tid];
        toks[tid] = tok;
        out_mask[n * TF_ + c * 16 + tid] = (ck && tok) ? 1.f : 0.f;
    }
    __syncthreads();

    #pragma unroll
    for (int i = 0; i < 4; ++i) {
        const int t = w * 4 + i;
        const int tok = toks[t];                 // wave-uniform branch
        float4 v = {0.f, 0.f, 0.f, 0.f};
        if (ck && tok) v = embed4[(size_t)tok * D4_ + l];
        out_enc4[((size_t)n * TF_ + c * 16 + t) * D4_ + l] = v;
    }
}

// ---------------------------------------------------------------------------
extern "C" void kernel_launch(void* const* d_in, const int* in_sizes, int n_in,
                              void* d_out, int out_size, void* d_ws, size_t ws_size,
                              hipStream_t stream) {
    const int*    src      = (const int*)d_in[0];    // [N,TC]
    const int*    know     = (const int*)d_in[1];    // [N,K,TK]
    const int*    ckm      = (const int*)d_in[2];    // [N,K]
    const int*    cs_ids   = (const int*)d_in[3];    // [N]
    const int*    use_flag = (const int*)d_in[4];    // scalar
    const float4* embed4   = (const float4*)d_in[5]; // [V,D] viewed as [V,D/4]

    float*  out      = (float*)d_out;
    float4* out_enc4 = (float4*)out;                         // [N,TF,D/4]
    float*  out_mask = out + (size_t)N_ * TF_ * D_;          // [N,TF]
    float*  out_attn = out_mask + (size_t)N_ * TF_;          // [N,K]

    float4* ws_part4 = (float4*)d_ws;                        // [N*8, D/4]
    int*    ws_clen  = (int*)((float*)d_ws + (size_t)N_ * 8 * D_);  // [N*8]
    float*  ws_score = (float*)(ws_clen + N_ * 8);           // [N,K]

    hipLaunchKernelGGL(kA_ctx, dim3(N_ * 8), dim3(256), 0, stream,
                       src, embed4, out_enc4, out_mask, ws_part4, ws_clen);
    hipLaunchKernelGGL(kB_know, dim3(N_ * K_), dim3(256), 0, stream,
                       know, ckm, embed4, ws_part4, ws_clen, out_attn, ws_score);
    hipLaunchKernelGGL(kC_sel, dim3(N_ * 4), dim3(256), 0, stream,
                       know, ckm, cs_ids, use_flag, embed4, ws_score,
                       out_enc4, out_mask);
}